// Round 7
// baseline (948.234 us; speedup 1.0000x reference)
//
#include <hip/hip_runtime.h>

// RGCN 2-layer forward for MI355X (gfx950). N=50000, D=128, R=16, E=1600000.
//
// Round-6 counters: fill_kernel 115us with 109MB WRITE for 6.4MB payload
// (cross-XCD 4B-scatter line amplification); msg round-trip ~819MB HBM.
// Round-7:
//   sort: two-level LDS-aggregated counting sort (coarse 4096-key buckets ->
//         per-bucket local hist/scan/scatter). No global hist, no global scans.
//   gemm: gather-mean fused into MFMA GEMM. Per 64-row block, per relation:
//         stage B (32KB swizzled) + gathered A-tile (16KB, fragment order)
//         into LDS, then 16x16x32 bf16 MFMA. No msg buffer, no acc buffer.
//
// ws: h_bf | x_bf | Wt1 | Wt2 | seg_off(M+1) | cnt_inv(M) | sorted_src(E) |
//     coarse_buf(E uint2) | coarse_cnt | cscan | coarse_cursor

#define ND 128
#define NR 16
#define KPB 4096              // keys per coarse bucket

typedef __attribute__((ext_vector_type(8))) short bf16x8;
typedef __attribute__((ext_vector_type(4))) float f32x4;

__device__ __forceinline__ unsigned short f2b(float f) {
    unsigned u = __float_as_uint(f);
    u += 0x7FFFu + ((u >> 16) & 1u);          // round-to-nearest-even
    return (unsigned short)(u >> 16);
}

// ------------------------------------------------------------ coarse hist ---
__global__ __launch_bounds__(256) void coarse_hist(
    const int* __restrict__ dst, const int* __restrict__ rel,
    int* __restrict__ coarse_cnt, int E, int N, int NBK)
{
    __shared__ int h[1024];
    const int t = threadIdx.x;
    for (int i = t; i < NBK; i += 256) h[i] = 0;
    __syncthreads();
#pragma unroll
    for (int q = 0; q < 16; ++q) {
        int e = blockIdx.x * KPB + q * 256 + t;
        if (e < E) {
            int key = rel[e] * N + dst[e];
            atomicAdd(&h[key >> 12], 1);
        }
    }
    __syncthreads();
    for (int i = t; i < NBK; i += 256)
        if (h[i]) atomicAdd(&coarse_cnt[i], h[i]);
}

// ------------------------------------------------------------ coarse scan ---
__global__ __launch_bounds__(1024) void coarse_scan(
    const int* __restrict__ coarse_cnt, int* __restrict__ cscan,
    int* __restrict__ coarse_cursor, int NBK, int E)
{
    __shared__ int sdata[1024];
    const int t = threadIdx.x;
    int v = (t < NBK) ? coarse_cnt[t] : 0;
    sdata[t] = v;
    __syncthreads();
    for (int off = 1; off < 1024; off <<= 1) {
        int tmp = (t >= off) ? sdata[t - off] : 0;
        __syncthreads();
        sdata[t] += tmp;
        __syncthreads();
    }
    if (t < NBK) {
        int excl = sdata[t] - v;
        cscan[t] = excl;
        coarse_cursor[t] = excl;
    }
    if (t == 0) cscan[NBK] = E;
}

// --------------------------------------------------------- fill A (bucket) ---
// Block of 4096 edges: LDS hist by coarse bucket, reserve global ranges,
// scatter (src,key) pairs to coarse_buf in per-(block,bucket) runs.
__global__ __launch_bounds__(256) void fillA(
    const int* __restrict__ src, const int* __restrict__ dst,
    const int* __restrict__ rel, int* __restrict__ coarse_cursor,
    uint2* __restrict__ coarse_buf, int E, int N, int NBK)
{
    __shared__ uint2 pairs[KPB];
    __shared__ int h[1024];
    const int t = threadIdx.x;
    for (int i = t; i < NBK; i += 256) h[i] = 0;
    __syncthreads();
#pragma unroll
    for (int q = 0; q < 16; ++q) {
        int e = blockIdx.x * KPB + q * 256 + t;
        unsigned key = 0xFFFFFFFFu, sv = 0;
        if (e < E) {
            key = (unsigned)(rel[e] * N + dst[e]);
            sv = (unsigned)src[e];
            atomicAdd(&h[key >> 12], 1);
        }
        pairs[q * 256 + t] = make_uint2(sv, key);
    }
    __syncthreads();
    for (int i = t; i < NBK; i += 256) {
        int c = h[i];
        h[i] = c ? atomicAdd(&coarse_cursor[i], c) : 0;
    }
    __syncthreads();
#pragma unroll
    for (int q = 0; q < 16; ++q) {
        uint2 p = pairs[q * 256 + t];
        if (p.y != 0xFFFFFFFFu) {
            int pos = atomicAdd(&h[p.y >> 12], 1);
            coarse_buf[pos] = p;
        }
    }
}

// ---------------------------------------------- fill B (local sort+outputs) ---
// One block per coarse bucket: local 4096-key hist -> local scan (seeded with
// cscan[b]) -> writes seg_off + cnt_inv coalesced -> scatter sorted_src into
// the bucket's private contiguous window.
__global__ __launch_bounds__(256) void fillB(
    const uint2* __restrict__ coarse_buf, const int* __restrict__ cscan,
    int* __restrict__ seg_off, float* __restrict__ cnt_inv,
    int* __restrict__ sorted_src, int M, int E, int NBK)
{
    __shared__ int cnt[KPB];
    __shared__ int w[256];
    const int t = threadIdx.x;
    const int b = blockIdx.x;
    const int kbase = b << 12;
    const int nkeys = min(KPB, M - kbase);
    const int r0 = cscan[b], r1 = cscan[b + 1];

    for (int i = t; i < KPB; i += 256) cnt[i] = 0;
    __syncthreads();
    for (int e = r0 + t; e < r1; e += 256)
        atomicAdd(&cnt[coarse_buf[e].y - kbase], 1);
    __syncthreads();
    // cnt_inv (coalesced)
    for (int i = t; i < nkeys; i += 256)
        cnt_inv[kbase + i] = 1.0f / fmaxf((float)cnt[i], 1.0f);
    // local scan: per-thread chunk of 16, then 256-wide Hillis-Steele
    int s = 0;
#pragma unroll
    for (int j = 0; j < 16; ++j) s += cnt[t * 16 + j];
    w[t] = s;
    __syncthreads();
    for (int off = 1; off < 256; off <<= 1) {
        int tmp = (t >= off) ? w[t - off] : 0;
        __syncthreads();
        w[t] += tmp;
        __syncthreads();
    }
    int run = r0 + w[t] - s;    // global exclusive prefix for this chunk
#pragma unroll
    for (int j = 0; j < 16; ++j) {
        int i = t * 16 + j;
        int c = cnt[i];
        cnt[i] = run;           // becomes the scatter cursor
        if (i < nkeys) seg_off[kbase + i] = run;
        run += c;
    }
    if (b == NBK - 1 && t == 0) seg_off[M] = E;
    __syncthreads();
    for (int e = r0 + t; e < r1; e += 256) {
        uint2 p = coarse_buf[e];
        int pos = atomicAdd(&cnt[p.y - kbase], 1);
        sorted_src[pos] = (int)p.x;
    }
}

// --------------------------------------------------------------- convert ---
__global__ __launch_bounds__(256) void conv_x_kernel(
    const float* __restrict__ x, unsigned short* __restrict__ xb, int n4)
{
    int i = blockIdx.x * 256 + threadIdx.x;
    if (i >= n4) return;
    float4 v = ((const float4*)x)[i];
    uint2 o;
    o.x = (unsigned)f2b(v.x) | ((unsigned)f2b(v.y) << 16);
    o.y = (unsigned)f2b(v.z) | ((unsigned)f2b(v.w) << 16);
    ((uint2*)xb)[i] = o;
}

// Weights in MFMA-fragment order: Wt[mat][(kt*8+ct)*64+lane][8 shorts],
// frag(lane) = { n = ct*16 + (lane&15), k = kt*32 + (lane>>4)*8 .. +8 }.
__global__ __launch_bounds__(256) void conv_w_kernel(
    const float* __restrict__ W, const float* __restrict__ root,
    unsigned short* __restrict__ Wt)
{
    int t = blockIdx.x * 256 + threadIdx.x;   // one thread per 16B fragment
    if (t >= 17 * 2048) return;
    int mat = t >> 11;
    int f = t & 2047;
    int lane = f & 63;
    int ctkt = f >> 6;
    int kt = ctkt >> 3;
    int ct = ctkt & 7;
    int n = ct * 16 + (lane & 15);
    int k = kt * 32 + (lane >> 4) * 8;
    const float* s = (mat < 16) ? (W + (size_t)mat * 16384) : root;
    uint4 o;
    o.x = (unsigned)f2b(s[(size_t)(k + 0) * ND + n]) | ((unsigned)f2b(s[(size_t)(k + 1) * ND + n]) << 16);
    o.y = (unsigned)f2b(s[(size_t)(k + 2) * ND + n]) | ((unsigned)f2b(s[(size_t)(k + 3) * ND + n]) << 16);
    o.z = (unsigned)f2b(s[(size_t)(k + 4) * ND + n]) | ((unsigned)f2b(s[(size_t)(k + 5) * ND + n]) << 16);
    o.w = (unsigned)f2b(s[(size_t)(k + 6) * ND + n]) | ((unsigned)f2b(s[(size_t)(k + 7) * ND + n]) << 16);
    *(uint4*)(Wt + (size_t)t * 8) = o;
}

// ------------------------------------------------------------- fused gemm ---
// 256 threads = 4 waves; block covers 64 rows x 128 cols. Per relation
// (-1 = root): stage B (32KB swizzled from global) and the gathered A-tile
// (16KB, fragment order) into LDS, then each wave does 4x(1 a-read + 8
// b-reads + 8 MFMA). Gather: 16 lanes per segment, lane owns one 16B chunk;
// 4 rounds cover 64 segments. Accumulators live in registers for all 17 mats.
__global__ __launch_bounds__(256, 3) void gemm_fused(
    const unsigned short* __restrict__ A0,    // N x 128 bf16
    const int* __restrict__ seg_off,          // R*N+1
    const int* __restrict__ sorted_src,       // E
    const float* __restrict__ cnt_inv,        // R*N
    const unsigned short* __restrict__ Wt,    // [17][2048][8] swizzled
    const float* __restrict__ bias,
    unsigned short* __restrict__ out_bf,      // layer-1 dest or null
    float* __restrict__ out_f32,              // layer-2 dest or null
    int N)
{
    __shared__ __align__(16) unsigned short Bs[2048 * 8];   // 32 KB
    __shared__ __align__(16) unsigned short As[1024 * 8];   // 16 KB
    const int tid = threadIdx.x;
    const int lane = tid & 63;
    const int wv = tid >> 6;
    const int quad = lane >> 4;
    const int l16 = lane & 15;
    const int n0 = blockIdx.x * 64;
    const int c = tid & 15;          // gather: col chunk (8 cols = 16B)
    const int sgrp = tid >> 4;       // gather: segment sub-index (0..15)

    f32x4 acc[8];
#pragma unroll
    for (int ct = 0; ct < 8; ++ct) { f32x4 z = {0.f, 0.f, 0.f, 0.f}; acc[ct] = z; }

    for (int rel = -1; rel < NR; ++rel) {
        const int mat = (rel < 0) ? 16 : rel;
        const uint4* Bsrc = (const uint4*)(Wt + (size_t)mat * 2048 * 8);

        __syncthreads();   // previous relation's LDS reads complete
#pragma unroll
        for (int i = 0; i < 8; ++i)
            ((uint4*)Bs)[tid + i * 256] = Bsrc[tid + i * 256];

#pragma unroll
        for (int g = 0; g < 4; ++g) {
            int sg = g * 16 + sgrp;            // row within tile (0..63)
            int gn = n0 + sg;
            uint4 u = make_uint4(0, 0, 0, 0);
            if (gn < N) {
                if (rel < 0) {
                    u = *(const uint4*)(A0 + (size_t)gn * ND + c * 8);
                } else {
                    int s = rel * N + gn;
                    int b0 = seg_off[s], e1 = seg_off[s + 1];
                    if (b0 < e1) {
                        float a0 = 0.f, a1 = 0.f, a2 = 0.f, a3 = 0.f;
                        float a4 = 0.f, a5 = 0.f, a6 = 0.f, a7 = 0.f;
                        for (int e = b0; e < e1; ++e) {
                            int sr = sorted_src[e];
                            uint4 v = *(const uint4*)(A0 + (size_t)sr * ND + c * 8);
                            a0 += __uint_as_float(v.x << 16); a1 += __uint_as_float(v.x & 0xFFFF0000u);
                            a2 += __uint_as_float(v.y << 16); a3 += __uint_as_float(v.y & 0xFFFF0000u);
                            a4 += __uint_as_float(v.z << 16); a5 += __uint_as_float(v.z & 0xFFFF0000u);
                            a6 += __uint_as_float(v.w << 16); a7 += __uint_as_float(v.w & 0xFFFF0000u);
                        }
                        float inv = cnt_inv[s];
                        u.x = (unsigned)f2b(a0 * inv) | ((unsigned)f2b(a1 * inv) << 16);
                        u.y = (unsigned)f2b(a2 * inv) | ((unsigned)f2b(a3 * inv) << 16);
                        u.z = (unsigned)f2b(a4 * inv) | ((unsigned)f2b(a5 * inv) << 16);
                        u.w = (unsigned)f2b(a6 * inv) | ((unsigned)f2b(a7 * inv) << 16);
                    }
                }
            }
            // fragment position: row sg, k-chunk c
            int fi = (((sg >> 4) * 4 + (c >> 2)) * 64) + ((c & 3) * 16) + (sg & 15);
            *(uint4*)(As + (size_t)fi * 8) = u;
        }
        __syncthreads();

#pragma unroll
        for (int kt = 0; kt < 4; ++kt) {
            bf16x8 a = *(const bf16x8*)(As + (size_t)((wv * 4 + kt) * 64 + lane) * 8);
#pragma unroll
            for (int ct = 0; ct < 8; ++ct) {
                bf16x8 b = *(const bf16x8*)(Bs + (size_t)((kt * 8 + ct) * 64 + lane) * 8);
                acc[ct] = __builtin_amdgcn_mfma_f32_16x16x32_bf16(a, b, acc[ct], 0, 0, 0);
            }
        }
    }

    const int m0 = n0 + wv * 16;
#pragma unroll
    for (int ct = 0; ct < 8; ++ct) {
        float bb = bias[ct * 16 + l16];
#pragma unroll
        for (int rg = 0; rg < 4; ++rg) {
            int r = m0 + quad * 4 + rg;
            if (r < N) {
                float v = fmaxf(acc[ct][rg] + bb, 0.f);
                if (out_bf) out_bf[(size_t)r * ND + ct * 16 + l16] = f2b(v);
                else        out_f32[(size_t)r * ND + ct * 16 + l16] = v;
            }
        }
    }
}

// ----------------------------------------------------------------- launch ---
extern "C" void kernel_launch(void* const* d_in, const int* in_sizes, int n_in,
                              void* d_out, int out_size, void* d_ws, size_t ws_size,
                              hipStream_t stream) {
    const float* x     = (const float*)d_in[0];
    const int*   eidx  = (const int*)d_in[1];
    const int*   etype = (const int*)d_in[2];
    const float* W1    = (const float*)d_in[3];
    const float* root1 = (const float*)d_in[4];
    const float* b1    = (const float*)d_in[5];
    const float* W2    = (const float*)d_in[6];
    const float* root2 = (const float*)d_in[7];
    const float* b2    = (const float*)d_in[8];
    float* out = (float*)d_out;

    const int N = in_sizes[0] / ND;
    const int E = in_sizes[2];
    const int M = NR * N;
    const int NBK = (M + KPB - 1) / KPB;     // 196 coarse buckets

    const int* src = eidx;
    const int* dst = eidx + E;

    // --- workspace carve-up (~53 MB) ---
    char* p = (char*)d_ws;
    auto carve = [&](size_t bytes) { char* q = p; p += (bytes + 255) & ~(size_t)255; return q; };
    unsigned short* h_bf    = (unsigned short*)carve((size_t)N * ND * 2);
    unsigned short* x_bf    = (unsigned short*)carve((size_t)N * ND * 2);
    unsigned short* Wt1     = (unsigned short*)carve((size_t)17 * 2048 * 8 * 2);
    unsigned short* Wt2     = (unsigned short*)carve((size_t)17 * 2048 * 8 * 2);
    int*   seg_off          = (int*)  carve((size_t)(M + 1) * 4);
    float* cnt_inv          = (float*)carve((size_t)M * 4);
    int*   sorted_src       = (int*)  carve((size_t)E * 4);
    uint2* coarse_buf       = (uint2*)carve((size_t)E * 8);
    int*   coarse_cnt       = (int*)  carve(1024 * 4);
    int*   cscan            = (int*)  carve(1025 * 4);
    int*   coarse_cursor    = (int*)  carve(1024 * 4);

    const int eb4 = (E + KPB - 1) / KPB;     // 391 edge blocks
    const int gemm_blocks = (N + 63) / 64;   // 782

    // --- two-level counting sort by (rel, dst) ---
    hipMemsetAsync(coarse_cnt, 0, 1024 * 4, stream);
    coarse_hist<<<eb4, 256, 0, stream>>>(dst, etype, coarse_cnt, E, N, NBK);
    coarse_scan<<<1, 1024, 0, stream>>>(coarse_cnt, cscan, coarse_cursor, NBK, E);
    fillA<<<eb4, 256, 0, stream>>>(src, dst, etype, coarse_cursor, coarse_buf, E, N, NBK);
    fillB<<<NBK, 256, 0, stream>>>(coarse_buf, cscan, seg_off, cnt_inv, sorted_src, M, E, NBK);

    // --- bf16 conversions ---
    conv_x_kernel<<<((N * ND / 4) + 255) / 256, 256, 0, stream>>>(x, x_bf, N * ND / 4);
    conv_w_kernel<<<(17 * 2048 + 255) / 256, 256, 0, stream>>>(W1, root1, Wt1);
    conv_w_kernel<<<(17 * 2048 + 255) / 256, 256, 0, stream>>>(W2, root2, Wt2);

    // --- layer 1: x -> h (bf16),  layer 2: h -> out (f32) ---
    gemm_fused<<<gemm_blocks, 256, 0, stream>>>(
        x_bf, seg_off, sorted_src, cnt_inv, Wt1, b1, h_bf, (float*)nullptr, N);
    gemm_fused<<<gemm_blocks, 256, 0, stream>>>(
        h_bf, seg_off, sorted_src, cnt_inv, Wt2, b2, (unsigned short*)nullptr, out, N);
}

// Round 8
// 519.138 us; speedup vs baseline: 1.8266x; 1.8266x over previous
//
#include <hip/hip_runtime.h>

// RGCN 2-layer forward for MI355X (gfx950). N=50000, D=128, R=16, E=1600000.
//
// Round-7 post-mortem: fusing gather into the GEMM serialized CSR-walk latency
// behind per-relation barriers (MfmaUtil 2.8%, 400us) + 16-way LDS write
// conflicts (1.19e7). Round-8 reverts to the proven split structure (R6,
// 583us) keeping R7's fast two-level sort, and fixes the gemm grid shape:
//   sort:   coarse 4096-key buckets (LDS hist) -> per-bucket local sort.
//   gather: 16-lane group per (rel,dst) segment -> bf16 msg chunk (C rels).
//   gemm:   256thr/64-row blocks (782 blocks ~ 3/CU), B staged in LDS
//           (lane*16B, conflict-free), A-fragments issued BEFORE the staging
//           barrier so global latency overlaps B staging. Multi-pass acc.
//
// ws: h_bf | x_bf | Wt1 | Wt2 | seg_off | cnt_inv | sorted_src | ctl |
//     union( coarse_buf , msg(C*N*128 bf16) + acc(N*128 f32 if C<16) )

#define ND 128
#define NR 16
#define KPB 4096              // keys per coarse bucket

typedef __attribute__((ext_vector_type(8))) short bf16x8;
typedef __attribute__((ext_vector_type(4))) float f32x4;

__device__ __forceinline__ unsigned short f2b(float f) {
    unsigned u = __float_as_uint(f);
    u += 0x7FFFu + ((u >> 16) & 1u);          // round-to-nearest-even
    return (unsigned short)(u >> 16);
}

// ------------------------------------------------------------ coarse hist ---
__global__ __launch_bounds__(256) void coarse_hist(
    const int* __restrict__ dst, const int* __restrict__ rel,
    int* __restrict__ coarse_cnt, int E, int N, int NBK)
{
    __shared__ int h[1024];
    const int t = threadIdx.x;
    for (int i = t; i < NBK; i += 256) h[i] = 0;
    __syncthreads();
#pragma unroll
    for (int q = 0; q < 16; ++q) {
        int e = blockIdx.x * KPB + q * 256 + t;
        if (e < E) {
            int key = rel[e] * N + dst[e];
            atomicAdd(&h[key >> 12], 1);
        }
    }
    __syncthreads();
    for (int i = t; i < NBK; i += 256)
        if (h[i]) atomicAdd(&coarse_cnt[i], h[i]);
}

// ------------------------------------------------------------ coarse scan ---
__global__ __launch_bounds__(1024) void coarse_scan(
    const int* __restrict__ coarse_cnt, int* __restrict__ cscan,
    int* __restrict__ coarse_cursor, int NBK, int E)
{
    __shared__ int sdata[1024];
    const int t = threadIdx.x;
    int v = (t < NBK) ? coarse_cnt[t] : 0;
    sdata[t] = v;
    __syncthreads();
    for (int off = 1; off < 1024; off <<= 1) {
        int tmp = (t >= off) ? sdata[t - off] : 0;
        __syncthreads();
        sdata[t] += tmp;
        __syncthreads();
    }
    if (t < NBK) {
        int excl = sdata[t] - v;
        cscan[t] = excl;
        coarse_cursor[t] = excl;
    }
    if (t == 0) cscan[NBK] = E;
}

// --------------------------------------------------------- fill A (bucket) ---
__global__ __launch_bounds__(256) void fillA(
    const int* __restrict__ src, const int* __restrict__ dst,
    const int* __restrict__ rel, int* __restrict__ coarse_cursor,
    uint2* __restrict__ coarse_buf, int E, int N, int NBK)
{
    __shared__ uint2 pairs[KPB];
    __shared__ int h[1024];
    const int t = threadIdx.x;
    for (int i = t; i < NBK; i += 256) h[i] = 0;
    __syncthreads();
#pragma unroll
    for (int q = 0; q < 16; ++q) {
        int e = blockIdx.x * KPB + q * 256 + t;
        unsigned key = 0xFFFFFFFFu, sv = 0;
        if (e < E) {
            key = (unsigned)(rel[e] * N + dst[e]);
            sv = (unsigned)src[e];
            atomicAdd(&h[key >> 12], 1);
        }
        pairs[q * 256 + t] = make_uint2(sv, key);
    }
    __syncthreads();
    for (int i = t; i < NBK; i += 256) {
        int c = h[i];
        h[i] = c ? atomicAdd(&coarse_cursor[i], c) : 0;
    }
    __syncthreads();
#pragma unroll
    for (int q = 0; q < 16; ++q) {
        uint2 p = pairs[q * 256 + t];
        if (p.y != 0xFFFFFFFFu) {
            int pos = atomicAdd(&h[p.y >> 12], 1);
            coarse_buf[pos] = p;
        }
    }
}

// ---------------------------------------------- fill B (local sort+outputs) ---
__global__ __launch_bounds__(256) void fillB(
    const uint2* __restrict__ coarse_buf, const int* __restrict__ cscan,
    int* __restrict__ seg_off, float* __restrict__ cnt_inv,
    int* __restrict__ sorted_src, int M, int E, int NBK)
{
    __shared__ int cnt[KPB];
    __shared__ int w[256];
    const int t = threadIdx.x;
    const int b = blockIdx.x;
    const int kbase = b << 12;
    const int nkeys = min(KPB, M - kbase);
    const int r0 = cscan[b], r1 = cscan[b + 1];

    for (int i = t; i < KPB; i += 256) cnt[i] = 0;
    __syncthreads();
    for (int e = r0 + t; e < r1; e += 256)
        atomicAdd(&cnt[coarse_buf[e].y - kbase], 1);
    __syncthreads();
    for (int i = t; i < nkeys; i += 256)
        cnt_inv[kbase + i] = 1.0f / fmaxf((float)cnt[i], 1.0f);
    int s = 0;
#pragma unroll
    for (int j = 0; j < 16; ++j) s += cnt[t * 16 + j];
    w[t] = s;
    __syncthreads();
    for (int off = 1; off < 256; off <<= 1) {
        int tmp = (t >= off) ? w[t - off] : 0;
        __syncthreads();
        w[t] += tmp;
        __syncthreads();
    }
    int run = r0 + w[t] - s;
#pragma unroll
    for (int j = 0; j < 16; ++j) {
        int i = t * 16 + j;
        int c = cnt[i];
        cnt[i] = run;
        if (i < nkeys) seg_off[kbase + i] = run;
        run += c;
    }
    if (b == NBK - 1 && t == 0) seg_off[M] = E;
    __syncthreads();
    for (int e = r0 + t; e < r1; e += 256) {
        uint2 p = coarse_buf[e];
        int pos = atomicAdd(&cnt[p.y - kbase], 1);
        sorted_src[pos] = (int)p.x;
    }
}

// --------------------------------------------------------------- convert ---
__global__ __launch_bounds__(256) void conv_x_kernel(
    const float* __restrict__ x, unsigned short* __restrict__ xb, int n4)
{
    int i = blockIdx.x * 256 + threadIdx.x;
    if (i >= n4) return;
    float4 v = ((const float4*)x)[i];
    uint2 o;
    o.x = (unsigned)f2b(v.x) | ((unsigned)f2b(v.y) << 16);
    o.y = (unsigned)f2b(v.z) | ((unsigned)f2b(v.w) << 16);
    ((uint2*)xb)[i] = o;
}

// Weights in MFMA-fragment order: Wt[mat][(kt*8+ct)*64+lane][8 shorts],
// frag(lane) = { n = ct*16 + (lane&15), k = kt*32 + (lane>>4)*8 .. +8 }.
__global__ __launch_bounds__(256) void conv_w_kernel(
    const float* __restrict__ W, const float* __restrict__ root,
    unsigned short* __restrict__ Wt)
{
    int t = blockIdx.x * 256 + threadIdx.x;
    if (t >= 17 * 2048) return;
    int mat = t >> 11;
    int f = t & 2047;
    int lane = f & 63;
    int ctkt = f >> 6;
    int kt = ctkt >> 3;
    int ct = ctkt & 7;
    int n = ct * 16 + (lane & 15);
    int k = kt * 32 + (lane >> 4) * 8;
    const float* s = (mat < 16) ? (W + (size_t)mat * 16384) : root;
    uint4 o;
    o.x = (unsigned)f2b(s[(size_t)(k + 0) * ND + n]) | ((unsigned)f2b(s[(size_t)(k + 1) * ND + n]) << 16);
    o.y = (unsigned)f2b(s[(size_t)(k + 2) * ND + n]) | ((unsigned)f2b(s[(size_t)(k + 3) * ND + n]) << 16);
    o.z = (unsigned)f2b(s[(size_t)(k + 4) * ND + n]) | ((unsigned)f2b(s[(size_t)(k + 5) * ND + n]) << 16);
    o.w = (unsigned)f2b(s[(size_t)(k + 6) * ND + n]) | ((unsigned)f2b(s[(size_t)(k + 7) * ND + n]) << 16);
    *(uint4*)(Wt + (size_t)t * 8) = o;
}

// ----------------------------------------------------------- gather mean ---
__global__ __launch_bounds__(256) void gather_mean(
    const unsigned short* __restrict__ A,    // N x 128 bf16
    const int* __restrict__ seg_off,
    const int* __restrict__ sorted_src,
    const float* __restrict__ cnt_inv,
    unsigned short* __restrict__ msg,        // cc x N x 128 bf16
    int N, int r0, int ccN)
{
    int g = blockIdx.x * 16 + (threadIdx.x >> 4);
    if (g >= ccN) return;
    int l = threadIdx.x & 15;
    int s = r0 * N + g;
    int b0 = seg_off[s], e1 = seg_off[s + 1];
    float a0 = 0.f, a1 = 0.f, a2 = 0.f, a3 = 0.f, a4 = 0.f, a5 = 0.f, a6 = 0.f, a7 = 0.f;
    int e = b0;
    for (; e + 2 <= e1; e += 2) {
        int s0 = sorted_src[e];
        int s1 = sorted_src[e + 1];
        uint4 u0 = *(const uint4*)(A + (size_t)s0 * ND + l * 8);
        uint4 u1 = *(const uint4*)(A + (size_t)s1 * ND + l * 8);
        a0 += __uint_as_float(u0.x << 16); a1 += __uint_as_float(u0.x & 0xFFFF0000u);
        a2 += __uint_as_float(u0.y << 16); a3 += __uint_as_float(u0.y & 0xFFFF0000u);
        a4 += __uint_as_float(u0.z << 16); a5 += __uint_as_float(u0.z & 0xFFFF0000u);
        a6 += __uint_as_float(u0.w << 16); a7 += __uint_as_float(u0.w & 0xFFFF0000u);
        a0 += __uint_as_float(u1.x << 16); a1 += __uint_as_float(u1.x & 0xFFFF0000u);
        a2 += __uint_as_float(u1.y << 16); a3 += __uint_as_float(u1.y & 0xFFFF0000u);
        a4 += __uint_as_float(u1.z << 16); a5 += __uint_as_float(u1.z & 0xFFFF0000u);
        a6 += __uint_as_float(u1.w << 16); a7 += __uint_as_float(u1.w & 0xFFFF0000u);
    }
    if (e < e1) {
        int s0 = sorted_src[e];
        uint4 u0 = *(const uint4*)(A + (size_t)s0 * ND + l * 8);
        a0 += __uint_as_float(u0.x << 16); a1 += __uint_as_float(u0.x & 0xFFFF0000u);
        a2 += __uint_as_float(u0.y << 16); a3 += __uint_as_float(u0.y & 0xFFFF0000u);
        a4 += __uint_as_float(u0.z << 16); a5 += __uint_as_float(u0.z & 0xFFFF0000u);
        a6 += __uint_as_float(u0.w << 16); a7 += __uint_as_float(u0.w & 0xFFFF0000u);
    }
    float inv = cnt_inv[s];
    uint4 o;
    o.x = (unsigned)f2b(a0 * inv) | ((unsigned)f2b(a1 * inv) << 16);
    o.y = (unsigned)f2b(a2 * inv) | ((unsigned)f2b(a3 * inv) << 16);
    o.z = (unsigned)f2b(a4 * inv) | ((unsigned)f2b(a5 * inv) << 16);
    o.w = (unsigned)f2b(a6 * inv) | ((unsigned)f2b(a7 * inv) << 16);
    *(uint4*)(msg + (size_t)g * ND + l * 8) = o;
}

// -------------------------------------------------------------- mfma gemm ---
// 256 threads = 4 waves; block covers 64 rows (wave wv: rows blk*64+wv*16).
// Per relation: issue the wave's 4 A-fragments (global, overlaps staging),
// stage 32 KB swizzled B into LDS, then 4x8 MFMA from ds_read_b128.
__global__ __launch_bounds__(256) void gemm_mfma(
    const unsigned short* __restrict__ msg,   // cc x N x 128 bf16
    const unsigned short* __restrict__ xb,    // N x 128 bf16 (root operand)
    const unsigned short* __restrict__ Wt,    // [17][2048][8] swizzled bf16
    const float* __restrict__ bias,
    float* __restrict__ acc_buf,              // N x 128 f32 (multi-pass)
    unsigned short* __restrict__ out_bf,      // layer-1 dest or null
    float* __restrict__ out_f32,              // layer-2 dest or null
    int N, int c0, int cc, int include_root, int load_acc, int finalize)
{
    __shared__ __align__(16) unsigned short Bs[2048 * 8];   // 32 KB
    const int tid = threadIdx.x;
    const int lane = tid & 63;
    const int wv = tid >> 6;
    const int quad = lane >> 4;
    const int l16 = lane & 15;
    const int m0 = blockIdx.x * 64 + wv * 16;
    const int arow = m0 + l16;

    f32x4 acc[8];
    if (load_acc) {
#pragma unroll
        for (int ct = 0; ct < 8; ++ct)
#pragma unroll
            for (int rg = 0; rg < 4; ++rg) {
                int r = m0 + quad * 4 + rg;
                acc[ct][rg] = (r < N) ? acc_buf[(size_t)r * ND + ct * 16 + l16] : 0.f;
            }
    } else {
#pragma unroll
        for (int ct = 0; ct < 8; ++ct) { f32x4 z = {0.f, 0.f, 0.f, 0.f}; acc[ct] = z; }
    }

    for (int rel = include_root ? -1 : 0; rel < cc; ++rel) {
        const unsigned short* A = (rel < 0) ? xb : msg + (size_t)rel * N * ND;
        const int mat = (rel < 0) ? 16 : (c0 + rel);
        const uint4* Bsrc = (const uint4*)(Wt + (size_t)mat * 2048 * 8);

        // issue A-fragments first: latency overlaps B staging below
        bf16x8 a[4];
#pragma unroll
        for (int kt = 0; kt < 4; ++kt) {
            bf16x8 z = {0, 0, 0, 0, 0, 0, 0, 0};
            a[kt] = (arow < N) ? *(const bf16x8*)(A + (size_t)arow * ND + kt * 32 + quad * 8) : z;
        }

        __syncthreads();   // previous relation's LDS reads complete
#pragma unroll
        for (int i = 0; i < 8; ++i)
            ((uint4*)Bs)[tid + i * 256] = Bsrc[tid + i * 256];
        __syncthreads();

#pragma unroll
        for (int kt = 0; kt < 4; ++kt) {
#pragma unroll
            for (int ct = 0; ct < 8; ++ct) {
                bf16x8 b = *(const bf16x8*)(Bs + (size_t)((kt * 8 + ct) * 64 + lane) * 8);
                acc[ct] = __builtin_amdgcn_mfma_f32_16x16x32_bf16(a[kt], b, acc[ct], 0, 0, 0);
            }
        }
    }

    if (!finalize) {
#pragma unroll
        for (int ct = 0; ct < 8; ++ct)
#pragma unroll
            for (int rg = 0; rg < 4; ++rg) {
                int r = m0 + quad * 4 + rg;
                if (r < N) acc_buf[(size_t)r * ND + ct * 16 + l16] = acc[ct][rg];
            }
    } else {
#pragma unroll
        for (int ct = 0; ct < 8; ++ct) {
            float bb = bias[ct * 16 + l16];
#pragma unroll
            for (int rg = 0; rg < 4; ++rg) {
                int r = m0 + quad * 4 + rg;
                if (r < N) {
                    float v = fmaxf(acc[ct][rg] + bb, 0.f);
                    if (out_bf) out_bf[(size_t)r * ND + ct * 16 + l16] = f2b(v);
                    else        out_f32[(size_t)r * ND + ct * 16 + l16] = v;
                }
            }
        }
    }
}

// ----------------------------------------------------------------- launch ---
extern "C" void kernel_launch(void* const* d_in, const int* in_sizes, int n_in,
                              void* d_out, int out_size, void* d_ws, size_t ws_size,
                              hipStream_t stream) {
    const float* x     = (const float*)d_in[0];
    const int*   eidx  = (const int*)d_in[1];
    const int*   etype = (const int*)d_in[2];
    const float* W1    = (const float*)d_in[3];
    const float* root1 = (const float*)d_in[4];
    const float* b1    = (const float*)d_in[5];
    const float* W2    = (const float*)d_in[6];
    const float* root2 = (const float*)d_in[7];
    const float* b2    = (const float*)d_in[8];
    float* out = (float*)d_out;

    const int N = in_sizes[0] / ND;
    const int E = in_sizes[2];
    const int M = NR * N;
    const int NBK = (M + KPB - 1) / KPB;

    const int* src = eidx;
    const int* dst = eidx + E;

    // --- workspace carve-up: fixed (~41 MB) + union region ---
    char* p = (char*)d_ws;
    auto carve = [&](size_t bytes) { char* q = p; p += (bytes + 255) & ~(size_t)255; return q; };
    unsigned short* h_bf    = (unsigned short*)carve((size_t)N * ND * 2);
    unsigned short* x_bf    = (unsigned short*)carve((size_t)N * ND * 2);
    unsigned short* Wt1     = (unsigned short*)carve((size_t)17 * 2048 * 8 * 2);
    unsigned short* Wt2     = (unsigned short*)carve((size_t)17 * 2048 * 8 * 2);
    int*   seg_off          = (int*)  carve((size_t)(M + 1) * 4);
    float* cnt_inv          = (float*)carve((size_t)M * 4);
    int*   sorted_src       = (int*)  carve((size_t)E * 4);
    int*   coarse_cnt       = (int*)  carve(1024 * 4);
    int*   cscan            = (int*)  carve(1025 * 4);
    int*   coarse_cursor    = (int*)  carve(1024 * 4);

    // union region: coarse_buf (sort phase) OR msg [+ acc if C<16] (gemm phase)
    size_t fixed = (size_t)(p - (char*)d_ws);
    size_t remain = (ws_size > fixed) ? ws_size - fixed : 0;
    size_t chunk_bytes = (size_t)N * ND * 2;
    size_t acc_bytes   = (size_t)N * ND * 4;
    int C = 2;
    if (remain >= 16 * chunk_bytes + 512) C = 16;
    else if (remain >= 8 * chunk_bytes + acc_bytes + 512) C = 8;
    else if (remain >= 4 * chunk_bytes + acc_bytes + 512) C = 4;
    uint2* coarse_buf       = (uint2*)p;                 // E*8 <= union size
    unsigned short* msg     = (unsigned short*)carve((size_t)C * chunk_bytes);
    float* acc              = (float*)((C < 16) ? carve(acc_bytes) : (char*)p);

    const int eb4 = (E + KPB - 1) / KPB;
    const int gemm_blocks = (N + 63) / 64;

    // --- two-level counting sort by (rel, dst) ---
    hipMemsetAsync(coarse_cnt, 0, 1024 * 4, stream);
    coarse_hist<<<eb4, 256, 0, stream>>>(dst, etype, coarse_cnt, E, N, NBK);
    coarse_scan<<<1, 1024, 0, stream>>>(coarse_cnt, cscan, coarse_cursor, NBK, E);
    fillA<<<eb4, 256, 0, stream>>>(src, dst, etype, coarse_cursor, coarse_buf, E, N, NBK);
    fillB<<<NBK, 256, 0, stream>>>(coarse_buf, cscan, seg_off, cnt_inv, sorted_src, M, E, NBK);

    // --- bf16 conversions ---
    conv_x_kernel<<<((N * ND / 4) + 255) / 256, 256, 0, stream>>>(x, x_bf, N * ND / 4);
    conv_w_kernel<<<(17 * 2048 + 255) / 256, 256, 0, stream>>>(W1, root1, Wt1);
    conv_w_kernel<<<(17 * 2048 + 255) / 256, 256, 0, stream>>>(W2, root2, Wt2);

    // --- two layers, C relations per pass ---
    for (int layer = 0; layer < 2; ++layer) {
        const unsigned short* A  = (layer == 0) ? x_bf : h_bf;
        const unsigned short* Wt = (layer == 0) ? Wt1  : Wt2;
        const float* biasp       = (layer == 0) ? b1   : b2;

        for (int c0 = 0; c0 < NR; c0 += C) {
            int cc = (NR - c0 < C) ? (NR - c0) : C;
            int ccN = cc * N;
            gather_mean<<<(ccN + 15) / 16, 256, 0, stream>>>(
                A, seg_off, sorted_src, cnt_inv, msg, N, c0, ccN);
            int fin = (c0 + cc == NR) ? 1 : 0;
            gemm_mfma<<<gemm_blocks, 256, 0, stream>>>(
                msg, A, Wt, biasp, acc,
                (fin && layer == 0) ? h_bf : (unsigned short*)nullptr,
                (fin && layer == 1) ? out : (float*)nullptr,
                N, c0, cc, c0 == 0 ? 1 : 0, c0 > 0 ? 1 : 0, fin);
        }
    }
}